// Round 11
// baseline (139.691 us; speedup 1.0000x reference)
//
#include <hip/hip_runtime.h>
#include <hip/hip_bf16.h>

using u16 = unsigned short;
typedef __attribute__((ext_vector_type(8))) short bf16x8;
typedef __attribute__((ext_vector_type(4))) float f32x4;

static constexpr int N  = 2;
static constexpr int C  = 64;
static constexpr int H  = 256;
static constexpr int W  = 256;
static constexpr int Hd = 128;
static constexpr int Wd = 128;
static constexpr int KK = 25;
static constexpr int C2 = 256;
static constexpr int OC = 64;
static constexpr int HWP  = H * W;    // 65536
static constexpr int HDWD = Hd * Wd;  // 16384

__device__ __forceinline__ float bflo(unsigned u) { return __uint_as_float(u << 16); }
__device__ __forceinline__ float bfhi(unsigned u) { return __uint_as_float(u & 0xffff0000u); }
__device__ __forceinline__ unsigned pack2(float a, float b) {
    __hip_bfloat16 ha = __float2bfloat16(a), hb = __float2bfloat16(b);
    union { __hip_bfloat16 h; u16 u; } ua{ha}, ub{hb};
    return (unsigned)ua.u | ((unsigned)ub.u << 16);
}
__device__ __forceinline__ u16 f2bf(float f) {
    union { __hip_bfloat16 h; u16 u; } v{__float2bfloat16(f)};
    return v.u;
}
// async global->LDS DMA, 16B/lane; dest = wave-uniform base + lane*16 (m104)
__device__ __forceinline__ void gload16(const float* g, float* l) {
    __builtin_amdgcn_global_load_lds(
        (const __attribute__((address_space(1))) void*)g,
        (__attribute__((address_space(3))) void*)l, 16, 0, 0);
}

// ---------------- Kernel A: 1x1 down conv -> k1 PIXEL-MAJOR [n][px][cm] -----
// + fused weight-pack tail (former kW) on blocks 0..17: saves a launch+bubble.
__global__ __launch_bounds__(256) void kA_down(const float* __restrict__ x,
                                               const float* __restrict__ w,
                                               const float* __restrict__ b,
                                               u16* __restrict__ k1,
                                               const float* __restrict__ ew,
                                               const float* __restrict__ ow,
                                               u16* __restrict__ bfr,
                                               u16* __restrict__ bfr2) {
    __shared__ u16   xt[64][128];
    __shared__ float wt[64][66];
    const int tid = threadIdx.x;
    const int pg0 = blockIdx.x * 128;
    const int n   = pg0 >> 16;
    const int px0 = pg0 & (HWP - 1);

#pragma unroll
    for (int i = 0; i < 16; ++i) {
        int e  = i * 256 + tid;
        int cm = e >> 6, c = e & 63;
        wt[c][cm] = w[e];
    }
    const float* xb = x + (size_t)n * C * HWP + px0;
#pragma unroll
    for (int i = 0; i < 8; ++i) {
        int flat = i * 256 + tid;
        int row  = flat >> 5;
        int col4 = flat & 31;
        float4 v = *(const float4*)(xb + (size_t)row * HWP + col4 * 4);
        uint2 p;
        p.x = pack2(v.x, v.y);
        p.y = pack2(v.z, v.w);
        *(uint2*)&xt[row][col4 * 4] = p;
    }
    __syncthreads();

    const int cg  = tid & 7;
    const int pxg = tid >> 3;
    float acc[8][4];
#pragma unroll
    for (int j = 0; j < 8; ++j) {
        float bj = b[cg * 8 + j];
#pragma unroll
        for (int p = 0; p < 4; ++p) acc[j][p] = bj;
    }
#pragma unroll 8
    for (int c = 0; c < 64; ++c) {
        uint2 xv = *(const uint2*)&xt[c][pxg * 4];
        float xs[4] = {bflo(xv.x), bfhi(xv.x), bflo(xv.y), bfhi(xv.y)};
        float2 w01 = *(const float2*)&wt[c][cg * 8 + 0];
        float2 w23 = *(const float2*)&wt[c][cg * 8 + 2];
        float2 w45 = *(const float2*)&wt[c][cg * 8 + 4];
        float2 w67 = *(const float2*)&wt[c][cg * 8 + 6];
        float wv[8] = {w01.x, w01.y, w23.x, w23.y, w45.x, w45.y, w67.x, w67.y};
#pragma unroll
        for (int j = 0; j < 8; ++j)
#pragma unroll
            for (int p = 0; p < 4; ++p) acc[j][p] = fmaf(wv[j], xs[p], acc[j][p]);
    }
#pragma unroll
    for (int p = 0; p < 4; ++p) {
        uint4 o;
        o.x = pack2(acc[0][p], acc[1][p]);
        o.y = pack2(acc[2][p], acc[3][p]);
        o.z = pack2(acc[4][p], acc[5][p]);
        o.w = pack2(acc[6][p], acc[7][p]);
        *(uint4*)(k1 + ((size_t)pg0 + pxg * 4 + p) * 64 + cg * 8) = o;
    }

    // ---- fused weight pack (former kW), blocks 0..17 only ----
    if (blockIdx.x < 18) {
        int idx = blockIdx.x * 256 + tid;   // 0..4607
        if (idx < 2304) {
            int l  = idx & 63;
            int ft = idx >> 6;
            int t  = ft & 1, s = ft >> 1;
            int tap = s >> 1, h = s & 1;
            int c = l & 15, q = l >> 4;
            int kk = t * 16 + c;
            u16 o[8];
#pragma unroll
            for (int j = 0; j < 8; ++j) {
                int cm = 32 * h + 8 * q + j;
                float v = (kk < 25) ? ew[(kk * 64 + cm) * 9 + tap] : 0.f;
                o[j] = f2bf(v);
            }
            *(uint4*)(bfr + (size_t)idx * 8) = *(uint4*)o;
        } else if (idx < 4352) {
            int i2 = idx - 2304;
            int l  = i2 & 63;
            int ft = i2 >> 6;
            int nt = ft & 3, s = ft >> 2;
            int c = l & 15, q = l >> 4;
            int co = nt * 16 + c;
            u16 o[8];
#pragma unroll
            for (int j = 0; j < 8; ++j)
                o[j] = f2bf(ow[co * 256 + s * 32 + q * 8 + j]);
            *(uint4*)(bfr2 + (size_t)i2 * 8) = *(uint4*)o;
        }
    }
}

// -------- Kernel B2: enc conv as MFMA GEMM + in-register softmax ------------
__global__ __launch_bounds__(256) void kB2_enc(const u16* __restrict__ k1,
                                               const u16* __restrict__ bfr,
                                               const float* __restrict__ eb,
                                               float* __restrict__ ksm) {
    __shared__ u16 tile[3 * 130 * 72];
    const int tid = threadIdx.x;
    const int b   = blockIdx.x;
    const int half = b & 1;
    const int hd   = (b >> 1) & 127;
    const int n    = b >> 8;
    const int w0 = half * 64;
    const int xb = 2 * w0 - 1;
    const int y0 = 2 * hd - 1;
    const u16* kb = k1 + (size_t)n * HWP * 64;

    for (int r = 0; r < 13; ++r) {
        int f = r * 256 + tid;
        if (f < 3096) {
            int p  = f >> 3, ch = f & 7;
            int y  = p / 129, xi = p - y * 129;
            int yy = y0 + y, xx = xb + xi;
            uint4 v = make_uint4(0u, 0u, 0u, 0u);
            if (yy >= 0 && xx >= 0 && xx < 256)
                v = *(const uint4*)(kb + ((size_t)(yy * W + xx)) * 64 + ch * 8);
            *(uint4*)&tile[(y * 130 + xi) * 72 + ch * 8] = v;
        }
    }
    __syncthreads();

    const int wv = tid >> 6;
    const int l  = tid & 63;
    const int c  = l & 15;
    const int q  = l >> 4;

    f32x4 acc0 = {0.f, 0.f, 0.f, 0.f};
    f32x4 acc1 = {0.f, 0.f, 0.f, 0.f};
#pragma unroll
    for (int s = 0; s < 18; ++s) {
        const int tap = s >> 1, h = s & 1;
        const int dy = tap / 3, dx = tap - dy * 3;
        const u16* ap = &tile[(dy * 130 + 32 * wv + 2 * c + dx) * 72 + 32 * h + 8 * q];
        bf16x8 a  = *(const bf16x8*)ap;
        bf16x8 b0 = *(const bf16x8*)(bfr + ((size_t)(s * 2 + 0) * 64 + l) * 8);
        bf16x8 b1 = *(const bf16x8*)(bfr + ((size_t)(s * 2 + 1) * 64 + l) * 8);
        acc0 = __builtin_amdgcn_mfma_f32_16x16x32_bf16(a, b0, acc0, 0, 0, 0);
        acc1 = __builtin_amdgcn_mfma_f32_16x16x32_bf16(a, b1, acc1, 0, 0, 0);
    }

    const float e0 = eb[c];
    const float e1 = eb[min(16 + c, 24)];
    const bool c9 = (c < 9);

#pragma unroll
    for (int r = 0; r < 4; ++r) {
        float l0 = acc0[r] + e0;
        float l1 = c9 ? (acc1[r] + e1) : -1e30f;
        float mx = fmaxf(l0, l1);
#pragma unroll
        for (int d = 1; d < 16; d <<= 1) mx = fmaxf(mx, __shfl_xor(mx, d, 64));
        float x0 = __expf(l0 - mx);
        float x1 = c9 ? __expf(l1 - mx) : 0.f;
        float sm = x0 + x1;
#pragma unroll
        for (int d = 1; d < 16; d <<= 1) sm += __shfl_xor(sm, d, 64);
        float inv = 1.f / sm;
        int wd = w0 + 16 * wv + q * 4 + r;
        float* op = ksm + (size_t)n * KK * HDWD + hd * Wd + wd;
        op[(size_t)c * HDWD] = x0 * inv;
        if (c9) op[(size_t)(16 + c) * HDWD] = x1 * inv;
    }
}

// ---- Kernel C16: reassembly -> out2 CHUNK-MAJOR [n][cc32][px][8] -----------
// = kC15 (DMA staging, phased taps, 2 px/thread, 64-reg/32-wave point) with
// the block-index DECODE SWAPPED: hdt = b&15, cc = (b>>4)&31.
// Why: with cc fastest-varying (kC15), the 32 blocks sharing one (n,hdt)
// ksm tile (102.4 KB) round-robin across all 8 XCDs -> each XCD's private
// L2 fetches the same ksm from HBM -> ksm HBM traffic = 3.3MB x 8 ~= 26MB
// (the persistent FETCH excess: ~96MB vs ~70MB staged x). With hdt in the
// low bits, same-(n,hdt) blocks sit at b = hdt + 16*cc -> b%8 = hdt%8 ->
// ALL land on the same XCD; ksm fetched once per group. Bijective, zero
// arithmetic/register change. x traffic unaffected (cc-disjoint channels).
// GUARDRAIL: FETCH should drop ~96->~73MB; VGPR<=64, WRITE ~17.5MB.
__global__ __launch_bounds__(512, 4) void kC16_reassemble(const float* __restrict__ x,
                                                          const float* __restrict__ ksm,
                                                          u16* __restrict__ out2p) {
    __shared__ float xts[4 * 8 * 272];   // 34816 B: 4 strips x 8 rows x 272 cols
    const int tid = threadIdx.x;         // 0..511
    const int b   = blockIdx.x;
    const int hdt = b & 15;              // SWAPPED: hdt fastest-varying
    const int cc  = (b >> 4) & 31;       //          cc slow
    const int n   = b >> 9;
    const int hd0 = hdt * 8;
    const int t0  = hdt * 4;           // x-row base (per strip) for this tile
    const int hdo = tid >> 6;          // 0..7  (hd row within tile; wave-uniform)
    const int wdg = tid & 63;          // 0..63 (2-px group = lane)
    const int hd  = hd0 + hdo;
    const int wd0 = wdg * 2;
    const int wb  = ((hdo & 1) << 7) + wd0;  // x-col base (even)
    const int rloc = hdo >> 1;         // row offset within strip
    const int c0  = cc * 2;

    // zero pad columns once: data cols 2..3 (x cols -2..-1), 260..261 (256..257)
    if (tid < 64) {
        int rr = tid >> 1, side = tid & 1;
        int col = side ? 260 : 2;
        *(float2*)&xts[rr * 272 + col] = make_float2(0.f, 0.f);
    }

    const float* kb = ksm + (size_t)n * KK * HDWD + hd * Wd + wd0;

    // staging descriptors: 2048 16B slots = 4 strips x 8 rows x 64 lanes
    int  soff[4];
    bool sval[4];   // wave-uniform (depends only on s>>6)
#pragma unroll
    for (int k = 0; k < 4; ++k) {
        int s     = k * 512 + tid;
        int c4    = s & 63;
        int row   = (s >> 6) & 7;
        int strip = s >> 9;
        int y     = strip * 64 + t0 - 2 + row;
        sval[k]   = (y >= 0) & (y < H);
        int yc    = min(max(y, 0), H - 1);
        soff[k]   = yc * W + c4 * 4;
    }

    unsigned outw[2][4];   // 2 px x 4 u32 (8 bf16 c2 values per px)
    const float4 z4 = make_float4(0.f, 0.f, 0.f, 0.f);

#pragma unroll
    for (int ci = 0; ci < 2; ++ci) {
        __syncthreads();   // protect xts reuse (and pad init on ci=0)
        const float* base = x + (size_t)(n * C + c0 + ci) * HWP;
#pragma unroll
        for (int k = 0; k < 4; ++k) {
            int s = k * 512 + tid;
            int rowflat = s >> 6;                       // wave-uniform
            if (sval[k]) {
                gload16(base + soff[k], &xts[rowflat * 272 + 4]);
            } else {
                *(float4*)&xts[rowflat * 272 + 4 + (s & 63) * 4] = z4;
            }
        }
        __syncthreads();   // drains vmcnt(0): DMA complete for all waves

        float sq[4][2];
#pragma unroll
        for (int q = 0; q < 4; ++q) {
            sq[q][0] = 0.f; sq[q][1] = 0.f;
        }

#pragma unroll 1
        for (int ph = 0; ph < 5; ++ph) {        // one kernel-row per phase
            float2 kwc[5];                      // 5 taps x 2 px = 10 VGPRs
#pragma unroll
            for (int j = 0; j < 5; ++j)
                kwc[j] = *(const float2*)(kb + (size_t)(ph * 5 + j) * HDWD);
#pragma unroll
            for (int q = 0; q < 4; ++q) {
                const float* rp = &xts[(q * 8 + rloc + ph) * 272 + wb + 2];
                float2 r0 = *(const float2*)(rp + 0);   // 8B-aligned b64
                float2 r1 = *(const float2*)(rp + 2);
                float2 r2 = *(const float2*)(rp + 4);
                float f[6] = {r0.x, r0.y, r1.x, r1.y, r2.x, r2.y};
#pragma unroll
                for (int j = 0; j < 5; ++j) {
                    const float2 kv = kwc[j];
                    sq[q][0] = fmaf(f[j + 0], kv.x, sq[q][0]);
                    sq[q][1] = fmaf(f[j + 1], kv.y, sq[q][1]);
                }
            }
        }
#pragma unroll
        for (int r = 0; r < 2; ++r) {
            outw[r][ci * 2 + 0] = pack2(sq[0][r], sq[1][r]);
            outw[r][ci * 2 + 1] = pack2(sq[2][r], sq[3][r]);
        }
    }

    // private slab: 2 px x 16B = 32B contiguous per thread
    u16* dst = out2p + ((size_t)(n * 32 + cc) * HDWD + hd * Wd + wd0) * 8;
    *(uint4*)(dst + 0) = make_uint4(outw[0][0], outw[0][1], outw[0][2], outw[0][3]);
    *(uint4*)(dst + 8) = make_uint4(outw[1][0], outw[1][1], outw[1][2], outw[1][3]);
}

// ---- Kernel D3: 1x1 out conv as MFMA GEMM (chunk-major A) ------------------
// A element (px, c2) lives at ((n*32 + (c2>>3))*HDWD + px)*8 + (c2&7); the
// bf16x8 fragment (c2 = s*32+q*8 .. +7) is exactly one 16B record chunk at
// plane 4s+q -> 256B-contiguous segments per 16-lane group.
__global__ __launch_bounds__(256) void kD3_out(const u16* __restrict__ out2p,
                                               const u16* __restrict__ bfr2,
                                               const float* __restrict__ ob,
                                               float* __restrict__ out) {
    const int tid = threadIdx.x;
    const int b   = blockIdx.x;
    const int px0g = b * 64;
    const int n    = px0g >> 14;
    const int px0  = px0g & (HDWD - 1);
    const int nt = tid >> 6;
    const int l  = tid & 63;
    const int c  = l & 15;
    const int q  = l >> 4;

    const u16* An = out2p + (size_t)n * 32 * HDWD * 8;

    f32x4 acc[4] = {{0.f,0.f,0.f,0.f},{0.f,0.f,0.f,0.f},
                    {0.f,0.f,0.f,0.f},{0.f,0.f,0.f,0.f}};
#pragma unroll
    for (int s = 0; s < 8; ++s) {
        bf16x8 bf = *(const bf16x8*)(bfr2 + ((size_t)(s * 4 + nt) * 64 + l) * 8);
#pragma unroll
        for (int mt = 0; mt < 4; ++mt) {
            const u16* ap = An + ((size_t)(4 * s + q) * HDWD + px0 + mt * 16 + c) * 8;
            bf16x8 a = *(const bf16x8*)ap;
            acc[mt] = __builtin_amdgcn_mfma_f32_16x16x32_bf16(a, bf, acc[mt], 0, 0, 0);
        }
    }
    const int co = nt * 16 + c;
    const float bias = ob[co];
    float* ob_ = out + (size_t)(n * OC + co) * HDWD + px0;
#pragma unroll
    for (int mt = 0; mt < 4; ++mt)
#pragma unroll
        for (int r = 0; r < 4; ++r)
            ob_[mt * 16 + q * 4 + r] = acc[mt][r] + bias;
}

extern "C" void kernel_launch(void* const* d_in, const int* in_sizes, int n_in,
                              void* d_out, int out_size, void* d_ws, size_t ws_size,
                              hipStream_t stream) {
    const float* x  = (const float*)d_in[0];
    const float* dw = (const float*)d_in[1];
    const float* db = (const float*)d_in[2];
    const float* ew = (const float*)d_in[3];
    const float* eb = (const float*)d_in[4];
    const float* ow = (const float*)d_in[5];
    const float* ob = (const float*)d_in[6];
    float* out = (float*)d_out;

    char* ws = (char*)d_ws;
    u16*   k1    = (u16*)ws;                              // [n][px][cm] 16.8 MB
    float* ksm   = (float*)(ws + 16777216);               // 3.3 MB
    u16*   out2p = (u16*)(ws + 16777216 + 3276800);       // [n][cc][px][8] 16.8 MB
    u16*   bfr   = out2p;          // 36 KB: kA-tail writes, kB2 reads, kC16 clobbers
    u16*   bfr2  = (u16*)(ws + 16777216 + 3276800 + 16777216); // 32 KB own slot

    kA_down <<<dim3(1024), dim3(256), 0, stream>>>(x, dw, db, k1, ew, ow, bfr, bfr2);
    kB2_enc <<<dim3(512),  dim3(256), 0, stream>>>(k1, bfr, eb, ksm);
    kC16_reassemble<<<dim3(1024), dim3(512), 0, stream>>>(x, ksm, out2p);
    kD3_out <<<dim3(512),  dim3(256), 0, stream>>>(out2p, bfr2, ob, out);
}

// Round 12
// 139.639 us; speedup vs baseline: 1.0004x; 1.0004x over previous
//
#include <hip/hip_runtime.h>
#include <hip/hip_bf16.h>

using u16 = unsigned short;
typedef __attribute__((ext_vector_type(8))) short bf16x8;
typedef __attribute__((ext_vector_type(4))) float f32x4;

static constexpr int N  = 2;
static constexpr int C  = 64;
static constexpr int H  = 256;
static constexpr int W  = 256;
static constexpr int Hd = 128;
static constexpr int Wd = 128;
static constexpr int KK = 25;
static constexpr int C2 = 256;
static constexpr int OC = 64;
static constexpr int HWP  = H * W;    // 65536
static constexpr int HDWD = Hd * Wd;  // 16384

__device__ __forceinline__ float bflo(unsigned u) { return __uint_as_float(u << 16); }
__device__ __forceinline__ float bfhi(unsigned u) { return __uint_as_float(u & 0xffff0000u); }
__device__ __forceinline__ unsigned pack2(float a, float b) {
    __hip_bfloat16 ha = __float2bfloat16(a), hb = __float2bfloat16(b);
    union { __hip_bfloat16 h; u16 u; } ua{ha}, ub{hb};
    return (unsigned)ua.u | ((unsigned)ub.u << 16);
}
__device__ __forceinline__ u16 f2bf(float f) {
    union { __hip_bfloat16 h; u16 u; } v{__float2bfloat16(f)};
    return v.u;
}
// async global->LDS DMA, 16B/lane; dest = wave-uniform base + lane*16 (m104)
__device__ __forceinline__ void gload16(const float* g, float* l) {
    __builtin_amdgcn_global_load_lds(
        (const __attribute__((address_space(1))) void*)g,
        (__attribute__((address_space(3))) void*)l, 16, 0, 0);
}

// ---------------- Kernel A: 1x1 down conv -> k1 PIXEL-MAJOR [n][px][cm] -----
// + fused weight-pack tail (former kW) on blocks 0..17: saves a launch+bubble.
__global__ __launch_bounds__(256) void kA_down(const float* __restrict__ x,
                                               const float* __restrict__ w,
                                               const float* __restrict__ b,
                                               u16* __restrict__ k1,
                                               const float* __restrict__ ew,
                                               const float* __restrict__ ow,
                                               u16* __restrict__ bfr,
                                               u16* __restrict__ bfr2) {
    __shared__ u16   xt[64][128];
    __shared__ float wt[64][66];
    const int tid = threadIdx.x;
    const int pg0 = blockIdx.x * 128;
    const int n   = pg0 >> 16;
    const int px0 = pg0 & (HWP - 1);

#pragma unroll
    for (int i = 0; i < 16; ++i) {
        int e  = i * 256 + tid;
        int cm = e >> 6, c = e & 63;
        wt[c][cm] = w[e];
    }
    const float* xb = x + (size_t)n * C * HWP + px0;
#pragma unroll
    for (int i = 0; i < 8; ++i) {
        int flat = i * 256 + tid;
        int row  = flat >> 5;
        int col4 = flat & 31;
        float4 v = *(const float4*)(xb + (size_t)row * HWP + col4 * 4);
        uint2 p;
        p.x = pack2(v.x, v.y);
        p.y = pack2(v.z, v.w);
        *(uint2*)&xt[row][col4 * 4] = p;
    }
    __syncthreads();

    const int cg  = tid & 7;
    const int pxg = tid >> 3;
    float acc[8][4];
#pragma unroll
    for (int j = 0; j < 8; ++j) {
        float bj = b[cg * 8 + j];
#pragma unroll
        for (int p = 0; p < 4; ++p) acc[j][p] = bj;
    }
#pragma unroll 8
    for (int c = 0; c < 64; ++c) {
        uint2 xv = *(const uint2*)&xt[c][pxg * 4];
        float xs[4] = {bflo(xv.x), bfhi(xv.x), bflo(xv.y), bfhi(xv.y)};
        float2 w01 = *(const float2*)&wt[c][cg * 8 + 0];
        float2 w23 = *(const float2*)&wt[c][cg * 8 + 2];
        float2 w45 = *(const float2*)&wt[c][cg * 8 + 4];
        float2 w67 = *(const float2*)&wt[c][cg * 8 + 6];
        float wv[8] = {w01.x, w01.y, w23.x, w23.y, w45.x, w45.y, w67.x, w67.y};
#pragma unroll
        for (int j = 0; j < 8; ++j)
#pragma unroll
            for (int p = 0; p < 4; ++p) acc[j][p] = fmaf(wv[j], xs[p], acc[j][p]);
    }
#pragma unroll
    for (int p = 0; p < 4; ++p) {
        uint4 o;
        o.x = pack2(acc[0][p], acc[1][p]);
        o.y = pack2(acc[2][p], acc[3][p]);
        o.z = pack2(acc[4][p], acc[5][p]);
        o.w = pack2(acc[6][p], acc[7][p]);
        *(uint4*)(k1 + ((size_t)pg0 + pxg * 4 + p) * 64 + cg * 8) = o;
    }

    // ---- fused weight pack (former kW), blocks 0..17 only ----
    if (blockIdx.x < 18) {
        int idx = blockIdx.x * 256 + tid;   // 0..4607
        if (idx < 2304) {
            int l  = idx & 63;
            int ft = idx >> 6;
            int t  = ft & 1, s = ft >> 1;
            int tap = s >> 1, h = s & 1;
            int c = l & 15, q = l >> 4;
            int kk = t * 16 + c;
            u16 o[8];
#pragma unroll
            for (int j = 0; j < 8; ++j) {
                int cm = 32 * h + 8 * q + j;
                float v = (kk < 25) ? ew[(kk * 64 + cm) * 9 + tap] : 0.f;
                o[j] = f2bf(v);
            }
            *(uint4*)(bfr + (size_t)idx * 8) = *(uint4*)o;
        } else if (idx < 4352) {
            int i2 = idx - 2304;
            int l  = i2 & 63;
            int ft = i2 >> 6;
            int nt = ft & 3, s = ft >> 2;
            int c = l & 15, q = l >> 4;
            int co = nt * 16 + c;
            u16 o[8];
#pragma unroll
            for (int j = 0; j < 8; ++j)
                o[j] = f2bf(ow[co * 256 + s * 32 + q * 8 + j]);
            *(uint4*)(bfr2 + (size_t)i2 * 8) = *(uint4*)o;
        }
    }
}

// -------- Kernel B2: enc conv as MFMA GEMM + in-register softmax ------------
__global__ __launch_bounds__(256) void kB2_enc(const u16* __restrict__ k1,
                                               const u16* __restrict__ bfr,
                                               const float* __restrict__ eb,
                                               float* __restrict__ ksm) {
    __shared__ u16 tile[3 * 130 * 72];
    const int tid = threadIdx.x;
    const int b   = blockIdx.x;
    const int half = b & 1;
    const int hd   = (b >> 1) & 127;
    const int n    = b >> 8;
    const int w0 = half * 64;
    const int xb = 2 * w0 - 1;
    const int y0 = 2 * hd - 1;
    const u16* kb = k1 + (size_t)n * HWP * 64;

    for (int r = 0; r < 13; ++r) {
        int f = r * 256 + tid;
        if (f < 3096) {
            int p  = f >> 3, ch = f & 7;
            int y  = p / 129, xi = p - y * 129;
            int yy = y0 + y, xx = xb + xi;
            uint4 v = make_uint4(0u, 0u, 0u, 0u);
            if (yy >= 0 && xx >= 0 && xx < 256)
                v = *(const uint4*)(kb + ((size_t)(yy * W + xx)) * 64 + ch * 8);
            *(uint4*)&tile[(y * 130 + xi) * 72 + ch * 8] = v;
        }
    }
    __syncthreads();

    const int wv = tid >> 6;
    const int l  = tid & 63;
    const int c  = l & 15;
    const int q  = l >> 4;

    f32x4 acc0 = {0.f, 0.f, 0.f, 0.f};
    f32x4 acc1 = {0.f, 0.f, 0.f, 0.f};
#pragma unroll
    for (int s = 0; s < 18; ++s) {
        const int tap = s >> 1, h = s & 1;
        const int dy = tap / 3, dx = tap - dy * 3;
        const u16* ap = &tile[(dy * 130 + 32 * wv + 2 * c + dx) * 72 + 32 * h + 8 * q];
        bf16x8 a  = *(const bf16x8*)ap;
        bf16x8 b0 = *(const bf16x8*)(bfr + ((size_t)(s * 2 + 0) * 64 + l) * 8);
        bf16x8 b1 = *(const bf16x8*)(bfr + ((size_t)(s * 2 + 1) * 64 + l) * 8);
        acc0 = __builtin_amdgcn_mfma_f32_16x16x32_bf16(a, b0, acc0, 0, 0, 0);
        acc1 = __builtin_amdgcn_mfma_f32_16x16x32_bf16(a, b1, acc1, 0, 0, 0);
    }

    const float e0 = eb[c];
    const float e1 = eb[min(16 + c, 24)];
    const bool c9 = (c < 9);

#pragma unroll
    for (int r = 0; r < 4; ++r) {
        float l0 = acc0[r] + e0;
        float l1 = c9 ? (acc1[r] + e1) : -1e30f;
        float mx = fmaxf(l0, l1);
#pragma unroll
        for (int d = 1; d < 16; d <<= 1) mx = fmaxf(mx, __shfl_xor(mx, d, 64));
        float x0 = __expf(l0 - mx);
        float x1 = c9 ? __expf(l1 - mx) : 0.f;
        float sm = x0 + x1;
#pragma unroll
        for (int d = 1; d < 16; d <<= 1) sm += __shfl_xor(sm, d, 64);
        float inv = 1.f / sm;
        int wd = w0 + 16 * wv + q * 4 + r;
        float* op = ksm + (size_t)n * KK * HDWD + hd * Wd + wd;
        op[(size_t)c * HDWD] = x0 * inv;
        if (c9) op[(size_t)(16 + c) * HDWD] = x1 * inv;
    }
}

// ---- Kernel C18: reassembly -> out2 CHUNK-MAJOR [n][cc32][px][8] -----------
// kC15 (DMA staging, phased taps, 64-reg/32-wave regime, cc-fast decode --
// kC16's XCD swap was neutral: L3 already absorbs shared ksm) with 16-hd-row
// tiles to cut halo amplification: per strip 12 x-rows staged for 8 used
// (1.5x) vs 8-for-4 (2.0x) -> x FETCH ~66->~49 MB.
//  - 1024 threads (hdo = tid>>6 in 0..15), grid 512 = exactly 2 blocks/CU.
//  - LDS 4 strips x 12 rows x 272 = 52,224 B; 2 blocks fit; 32 waves/CU kept.
//  - LDS row index == sr = s>>6 (strip*12+row == sr), so DMA dest stays
//    wave-uniform base + lane*16 with no extra arithmetic.
//  - __launch_bounds__(1024, 8) pins the proven 64-reg bucket (R8 lesson).
//  - Per-px arithmetic order identical -> absmax must stay 0.03222656.
// GUARDRAIL: VGPR<=64, WRITE ~17.5MB, FETCH ~78MB; else revert to kC15.
__global__ __launch_bounds__(1024, 8) void kC18_reassemble(const float* __restrict__ x,
                                                           const float* __restrict__ ksm,
                                                           u16* __restrict__ out2p) {
    __shared__ float xts[4 * 12 * 272];  // 52224 B: 4 strips x 12 rows x 272 cols
    const int tid = threadIdx.x;         // 0..1023
    const int b   = blockIdx.x;
    const int cc  = b & 31;              // cc fastest (kC15 decode)
    const int hdt = (b >> 5) & 7;        // 8 tiles of 16 hd rows
    const int n   = b >> 8;
    const int t0  = hdt * 8;             // x-row base (per strip) for this tile
    const int hdo = tid >> 6;            // 0..15 (hd row within tile; wave-uniform)
    const int wdg = tid & 63;            // 0..63 (2-px group = lane)
    const int hd  = hdt * 16 + hdo;
    const int wd0 = wdg * 2;
    const int wb  = ((hdo & 1) << 7) + wd0;  // x-col base (even)
    const int rloc = hdo >> 1;           // 0..7 (row offset within strip)
    const int c0  = cc * 2;

    // zero pad columns once: data cols 2..3 (x cols -2..-1), 260..261 (256..257)
    if (tid < 96) {
        int rr = tid >> 1, side = tid & 1;
        int col = side ? 260 : 2;
        *(float2*)&xts[rr * 272 + col] = make_float2(0.f, 0.f);
    }

    const float* kb = ksm + (size_t)n * KK * HDWD + hd * Wd + wd0;

    // staging descriptors: 3072 16B slots = 4 strips x 12 rows x 64 lanes
    int  soff[3];
    bool sval[3];   // wave-uniform (depends only on s>>6)
#pragma unroll
    for (int k = 0; k < 3; ++k) {
        int s     = k * 1024 + tid;
        int c4    = s & 63;
        int sr    = s >> 6;              // 0..47, wave-uniform
        int strip = sr / 12;
        int row   = sr - strip * 12;     // 0..11
        int y     = strip * 64 + t0 - 2 + row;
        sval[k]   = (y >= 0) & (y < H);
        int yc    = min(max(y, 0), H - 1);
        soff[k]   = yc * W + c4 * 4;
    }

    unsigned outw[2][4];   // 2 px x 4 u32 (8 bf16 c2 values per px)
    const float4 z4 = make_float4(0.f, 0.f, 0.f, 0.f);

#pragma unroll
    for (int ci = 0; ci < 2; ++ci) {
        __syncthreads();   // protect xts reuse (and pad init on ci=0)
        const float* base = x + (size_t)(n * C + c0 + ci) * HWP;
#pragma unroll
        for (int k = 0; k < 3; ++k) {
            int s  = k * 1024 + tid;
            int sr = s >> 6;                            // wave-uniform LDS row
            if (sval[k]) {
                gload16(base + soff[k], &xts[sr * 272 + 4]);
            } else {
                *(float4*)&xts[sr * 272 + 4 + (s & 63) * 4] = z4;
            }
        }
        __syncthreads();   // drains vmcnt(0): DMA complete for all waves

        float sq[4][2];
#pragma unroll
        for (int q = 0; q < 4; ++q) {
            sq[q][0] = 0.f; sq[q][1] = 0.f;
        }

#pragma unroll 1
        for (int ph = 0; ph < 5; ++ph) {        // one kernel-row per phase
            float2 kwc[5];                      // 5 taps x 2 px = 10 VGPRs
#pragma unroll
            for (int j = 0; j < 5; ++j)
                kwc[j] = *(const float2*)(kb + (size_t)(ph * 5 + j) * HDWD);
#pragma unroll
            for (int q = 0; q < 4; ++q) {
                const float* rp = &xts[(q * 12 + rloc + ph) * 272 + wb + 2];
                float2 r0 = *(const float2*)(rp + 0);   // 8B-aligned b64
                float2 r1 = *(const float2*)(rp + 2);
                float2 r2 = *(const float2*)(rp + 4);
                float f[6] = {r0.x, r0.y, r1.x, r1.y, r2.x, r2.y};
#pragma unroll
                for (int j = 0; j < 5; ++j) {
                    const float2 kv = kwc[j];
                    sq[q][0] = fmaf(f[j + 0], kv.x, sq[q][0]);
                    sq[q][1] = fmaf(f[j + 1], kv.y, sq[q][1]);
                }
            }
        }
#pragma unroll
        for (int r = 0; r < 2; ++r) {
            outw[r][ci * 2 + 0] = pack2(sq[0][r], sq[1][r]);
            outw[r][ci * 2 + 1] = pack2(sq[2][r], sq[3][r]);
        }
    }

    // private slab: 2 px x 16B = 32B contiguous per thread
    u16* dst = out2p + ((size_t)(n * 32 + cc) * HDWD + hd * Wd + wd0) * 8;
    *(uint4*)(dst + 0) = make_uint4(outw[0][0], outw[0][1], outw[0][2], outw[0][3]);
    *(uint4*)(dst + 8) = make_uint4(outw[1][0], outw[1][1], outw[1][2], outw[1][3]);
}

// ---- Kernel D3: 1x1 out conv as MFMA GEMM (chunk-major A) ------------------
// A element (px, c2) lives at ((n*32 + (c2>>3))*HDWD + px)*8 + (c2&7); the
// bf16x8 fragment (c2 = s*32+q*8 .. +7) is exactly one 16B record chunk at
// plane 4s+q -> 256B-contiguous segments per 16-lane group.
__global__ __launch_bounds__(256) void kD3_out(const u16* __restrict__ out2p,
                                               const u16* __restrict__ bfr2,
                                               const float* __restrict__ ob,
                                               float* __restrict__ out) {
    const int tid = threadIdx.x;
    const int b   = blockIdx.x;
    const int px0g = b * 64;
    const int n    = px0g >> 14;
    const int px0  = px0g & (HDWD - 1);
    const int nt = tid >> 6;
    const int l  = tid & 63;
    const int c  = l & 15;
    const int q  = l >> 4;

    const u16* An = out2p + (size_t)n * 32 * HDWD * 8;

    f32x4 acc[4] = {{0.f,0.f,0.f,0.f},{0.f,0.f,0.f,0.f},
                    {0.f,0.f,0.f,0.f},{0.f,0.f,0.f,0.f}};
#pragma unroll
    for (int s = 0; s < 8; ++s) {
        bf16x8 bf = *(const bf16x8*)(bfr2 + ((size_t)(s * 4 + nt) * 64 + l) * 8);
#pragma unroll
        for (int mt = 0; mt < 4; ++mt) {
            const u16* ap = An + ((size_t)(4 * s + q) * HDWD + px0 + mt * 16 + c) * 8;
            bf16x8 a = *(const bf16x8*)ap;
            acc[mt] = __builtin_amdgcn_mfma_f32_16x16x32_bf16(a, bf, acc[mt], 0, 0, 0);
        }
    }
    const int co = nt * 16 + c;
    const float bias = ob[co];
    float* ob_ = out + (size_t)(n * OC + co) * HDWD + px0;
#pragma unroll
    for (int mt = 0; mt < 4; ++mt)
#pragma unroll
        for (int r = 0; r < 4; ++r)
            ob_[mt * 16 + q * 4 + r] = acc[mt][r] + bias;
}

extern "C" void kernel_launch(void* const* d_in, const int* in_sizes, int n_in,
                              void* d_out, int out_size, void* d_ws, size_t ws_size,
                              hipStream_t stream) {
    const float* x  = (const float*)d_in[0];
    const float* dw = (const float*)d_in[1];
    const float* db = (const float*)d_in[2];
    const float* ew = (const float*)d_in[3];
    const float* eb = (const float*)d_in[4];
    const float* ow = (const float*)d_in[5];
    const float* ob = (const float*)d_in[6];
    float* out = (float*)d_out;

    char* ws = (char*)d_ws;
    u16*   k1    = (u16*)ws;                              // [n][px][cm] 16.8 MB
    float* ksm   = (float*)(ws + 16777216);               // 3.3 MB
    u16*   out2p = (u16*)(ws + 16777216 + 3276800);       // [n][cc][px][8] 16.8 MB
    u16*   bfr   = out2p;          // 36 KB: kA-tail writes, kB2 reads, kC18 clobbers
    u16*   bfr2  = (u16*)(ws + 16777216 + 3276800 + 16777216); // 32 KB own slot

    kA_down <<<dim3(1024), dim3(256), 0, stream>>>(x, dw, db, k1, ew, ow, bfr, bfr2);
    kB2_enc <<<dim3(512),  dim3(256), 0, stream>>>(k1, bfr, eb, ksm);
    kC18_reassemble<<<dim3(512), dim3(1024), 0, stream>>>(x, ksm, out2p);
    kD3_out <<<dim3(512),  dim3(256), 0, stream>>>(out2p, bfr2, ob, out);
}

// Round 13
// 137.533 us; speedup vs baseline: 1.0157x; 1.0153x over previous
//
#include <hip/hip_runtime.h>
#include <hip/hip_bf16.h>

using u16 = unsigned short;
typedef __attribute__((ext_vector_type(8))) short bf16x8;
typedef __attribute__((ext_vector_type(4))) float f32x4;

static constexpr int N  = 2;
static constexpr int C  = 64;
static constexpr int H  = 256;
static constexpr int W  = 256;
static constexpr int Hd = 128;
static constexpr int Wd = 128;
static constexpr int KK = 25;
static constexpr int C2 = 256;
static constexpr int OC = 64;
static constexpr int HWP  = H * W;    // 65536
static constexpr int HDWD = Hd * Wd;  // 16384

__device__ __forceinline__ float bflo(unsigned u) { return __uint_as_float(u << 16); }
__device__ __forceinline__ float bfhi(unsigned u) { return __uint_as_float(u & 0xffff0000u); }
__device__ __forceinline__ unsigned pack2(float a, float b) {
    __hip_bfloat16 ha = __float2bfloat16(a), hb = __float2bfloat16(b);
    union { __hip_bfloat16 h; u16 u; } ua{ha}, ub{hb};
    return (unsigned)ua.u | ((unsigned)ub.u << 16);
}
__device__ __forceinline__ u16 f2bf(float f) {
    union { __hip_bfloat16 h; u16 u; } v{__float2bfloat16(f)};
    return v.u;
}
// async global->LDS DMA, 16B/lane; dest = wave-uniform base + lane*16 (m104)
__device__ __forceinline__ void gload16(const float* g, float* l) {
    __builtin_amdgcn_global_load_lds(
        (const __attribute__((address_space(1))) void*)g,
        (__attribute__((address_space(3))) void*)l, 16, 0, 0);
}

// ---------------- Kernel A: 1x1 down conv -> k1 PIXEL-MAJOR [n][px][cm] -----
// + fused weight-pack tail (former kW) on blocks 0..17: saves a launch+bubble.
__global__ __launch_bounds__(256) void kA_down(const float* __restrict__ x,
                                               const float* __restrict__ w,
                                               const float* __restrict__ b,
                                               u16* __restrict__ k1,
                                               const float* __restrict__ ew,
                                               const float* __restrict__ ow,
                                               u16* __restrict__ bfr,
                                               u16* __restrict__ bfr2) {
    __shared__ u16   xt[64][128];
    __shared__ float wt[64][66];
    const int tid = threadIdx.x;
    const int pg0 = blockIdx.x * 128;
    const int n   = pg0 >> 16;
    const int px0 = pg0 & (HWP - 1);

#pragma unroll
    for (int i = 0; i < 16; ++i) {
        int e  = i * 256 + tid;
        int cm = e >> 6, c = e & 63;
        wt[c][cm] = w[e];
    }
    const float* xb = x + (size_t)n * C * HWP + px0;
#pragma unroll
    for (int i = 0; i < 8; ++i) {
        int flat = i * 256 + tid;
        int row  = flat >> 5;
        int col4 = flat & 31;
        float4 v = *(const float4*)(xb + (size_t)row * HWP + col4 * 4);
        uint2 p;
        p.x = pack2(v.x, v.y);
        p.y = pack2(v.z, v.w);
        *(uint2*)&xt[row][col4 * 4] = p;
    }
    __syncthreads();

    const int cg  = tid & 7;
    const int pxg = tid >> 3;
    float acc[8][4];
#pragma unroll
    for (int j = 0; j < 8; ++j) {
        float bj = b[cg * 8 + j];
#pragma unroll
        for (int p = 0; p < 4; ++p) acc[j][p] = bj;
    }
#pragma unroll 8
    for (int c = 0; c < 64; ++c) {
        uint2 xv = *(const uint2*)&xt[c][pxg * 4];
        float xs[4] = {bflo(xv.x), bfhi(xv.x), bflo(xv.y), bfhi(xv.y)};
        float2 w01 = *(const float2*)&wt[c][cg * 8 + 0];
        float2 w23 = *(const float2*)&wt[c][cg * 8 + 2];
        float2 w45 = *(const float2*)&wt[c][cg * 8 + 4];
        float2 w67 = *(const float2*)&wt[c][cg * 8 + 6];
        float wv[8] = {w01.x, w01.y, w23.x, w23.y, w45.x, w45.y, w67.x, w67.y};
#pragma unroll
        for (int j = 0; j < 8; ++j)
#pragma unroll
            for (int p = 0; p < 4; ++p) acc[j][p] = fmaf(wv[j], xs[p], acc[j][p]);
    }
#pragma unroll
    for (int p = 0; p < 4; ++p) {
        uint4 o;
        o.x = pack2(acc[0][p], acc[1][p]);
        o.y = pack2(acc[2][p], acc[3][p]);
        o.z = pack2(acc[4][p], acc[5][p]);
        o.w = pack2(acc[6][p], acc[7][p]);
        *(uint4*)(k1 + ((size_t)pg0 + pxg * 4 + p) * 64 + cg * 8) = o;
    }

    // ---- fused weight pack (former kW), blocks 0..17 only ----
    if (blockIdx.x < 18) {
        int idx = blockIdx.x * 256 + tid;   // 0..4607
        if (idx < 2304) {
            int l  = idx & 63;
            int ft = idx >> 6;
            int t  = ft & 1, s = ft >> 1;
            int tap = s >> 1, h = s & 1;
            int c = l & 15, q = l >> 4;
            int kk = t * 16 + c;
            u16 o[8];
#pragma unroll
            for (int j = 0; j < 8; ++j) {
                int cm = 32 * h + 8 * q + j;
                float v = (kk < 25) ? ew[(kk * 64 + cm) * 9 + tap] : 0.f;
                o[j] = f2bf(v);
            }
            *(uint4*)(bfr + (size_t)idx * 8) = *(uint4*)o;
        } else if (idx < 4352) {
            int i2 = idx - 2304;
            int l  = i2 & 63;
            int ft = i2 >> 6;
            int nt = ft & 3, s = ft >> 2;
            int c = l & 15, q = l >> 4;
            int co = nt * 16 + c;
            u16 o[8];
#pragma unroll
            for (int j = 0; j < 8; ++j)
                o[j] = f2bf(ow[co * 256 + s * 32 + q * 8 + j]);
            *(uint4*)(bfr2 + (size_t)i2 * 8) = *(uint4*)o;
        }
    }
}

// -------- Kernel B2: enc conv as MFMA GEMM + in-register softmax ------------
__global__ __launch_bounds__(256) void kB2_enc(const u16* __restrict__ k1,
                                               const u16* __restrict__ bfr,
                                               const float* __restrict__ eb,
                                               float* __restrict__ ksm) {
    __shared__ u16 tile[3 * 130 * 72];
    const int tid = threadIdx.x;
    const int b   = blockIdx.x;
    const int half = b & 1;
    const int hd   = (b >> 1) & 127;
    const int n    = b >> 8;
    const int w0 = half * 64;
    const int xb = 2 * w0 - 1;
    const int y0 = 2 * hd - 1;
    const u16* kb = k1 + (size_t)n * HWP * 64;

    for (int r = 0; r < 13; ++r) {
        int f = r * 256 + tid;
        if (f < 3096) {
            int p  = f >> 3, ch = f & 7;
            int y  = p / 129, xi = p - y * 129;
            int yy = y0 + y, xx = xb + xi;
            uint4 v = make_uint4(0u, 0u, 0u, 0u);
            if (yy >= 0 && xx >= 0 && xx < 256)
                v = *(const uint4*)(kb + ((size_t)(yy * W + xx)) * 64 + ch * 8);
            *(uint4*)&tile[(y * 130 + xi) * 72 + ch * 8] = v;
        }
    }
    __syncthreads();

    const int wv = tid >> 6;
    const int l  = tid & 63;
    const int c  = l & 15;
    const int q  = l >> 4;

    f32x4 acc0 = {0.f, 0.f, 0.f, 0.f};
    f32x4 acc1 = {0.f, 0.f, 0.f, 0.f};
#pragma unroll
    for (int s = 0; s < 18; ++s) {
        const int tap = s >> 1, h = s & 1;
        const int dy = tap / 3, dx = tap - dy * 3;
        const u16* ap = &tile[(dy * 130 + 32 * wv + 2 * c + dx) * 72 + 32 * h + 8 * q];
        bf16x8 a  = *(const bf16x8*)ap;
        bf16x8 b0 = *(const bf16x8*)(bfr + ((size_t)(s * 2 + 0) * 64 + l) * 8);
        bf16x8 b1 = *(const bf16x8*)(bfr + ((size_t)(s * 2 + 1) * 64 + l) * 8);
        acc0 = __builtin_amdgcn_mfma_f32_16x16x32_bf16(a, b0, acc0, 0, 0, 0);
        acc1 = __builtin_amdgcn_mfma_f32_16x16x32_bf16(a, b1, acc1, 0, 0, 0);
    }

    const float e0 = eb[c];
    const float e1 = eb[min(16 + c, 24)];
    const bool c9 = (c < 9);

#pragma unroll
    for (int r = 0; r < 4; ++r) {
        float l0 = acc0[r] + e0;
        float l1 = c9 ? (acc1[r] + e1) : -1e30f;
        float mx = fmaxf(l0, l1);
#pragma unroll
        for (int d = 1; d < 16; d <<= 1) mx = fmaxf(mx, __shfl_xor(mx, d, 64));
        float x0 = __expf(l0 - mx);
        float x1 = c9 ? __expf(l1 - mx) : 0.f;
        float sm = x0 + x1;
#pragma unroll
        for (int d = 1; d < 16; d <<= 1) sm += __shfl_xor(sm, d, 64);
        float inv = 1.f / sm;
        int wd = w0 + 16 * wv + q * 4 + r;
        float* op = ksm + (size_t)n * KK * HDWD + hd * Wd + wd;
        op[(size_t)c * HDWD] = x0 * inv;
        if (c9) op[(size_t)(16 + c) * HDWD] = x1 * inv;
    }
}

// ---- Kernel C15: reassembly -> out2 CHUNK-MAJOR [n][cc32][px][8] -----------
// PROVEN BEST (R10: 137.7 us total). The session's terminal configuration:
//  - 2 px/thread, 512 threads, 64-reg/32-wave occupancy point (beats both
//    the 128-reg/16-wave point [R9] and any spill [R2/R3/R5/R8]).
//  - phased tap loads (unroll 1): only 10 live kw regs; full residency or
//    ping-pong tips the 64-reg bucket.
//  - x-staging via global_load_lds DMA (no VGPR round-trip); data window
//    at col 4 so every row base is 16B-aligned; __syncthreads drains vmcnt.
//  - private 256KB output slab per block: no cross-XCD line RMW.
//  - cc-fast decode (kC16's XCD co-location swap was neutral: L3 absorbs
//    shared ksm); 8-row tiles (kC18's 16-row tiles traded parallelism for
//    traffic and lost).
__global__ __launch_bounds__(512, 4) void kC15_reassemble(const float* __restrict__ x,
                                                          const float* __restrict__ ksm,
                                                          u16* __restrict__ out2p) {
    __shared__ float xts[4 * 8 * 272];   // 34816 B: 4 strips x 8 rows x 272 cols
    const int tid = threadIdx.x;         // 0..511
    const int b   = blockIdx.x;
    const int cc  = b & 31;
    const int hdt = (b >> 5) & 15;
    const int n   = b >> 9;
    const int hd0 = hdt * 8;
    const int t0  = hdt * 4;           // x-row base (per strip) for this tile
    const int hdo = tid >> 6;          // 0..7  (hd row within tile; wave-uniform)
    const int wdg = tid & 63;          // 0..63 (2-px group = lane)
    const int hd  = hd0 + hdo;
    const int wd0 = wdg * 2;
    const int wb  = ((hdo & 1) << 7) + wd0;  // x-col base (even)
    const int rloc = hdo >> 1;         // row offset within strip
    const int c0  = cc * 2;

    // zero pad columns once: data cols 2..3 (x cols -2..-1), 260..261 (256..257)
    if (tid < 64) {
        int rr = tid >> 1, side = tid & 1;
        int col = side ? 260 : 2;
        *(float2*)&xts[rr * 272 + col] = make_float2(0.f, 0.f);
    }

    const float* kb = ksm + (size_t)n * KK * HDWD + hd * Wd + wd0;

    // staging descriptors: 2048 16B slots = 4 strips x 8 rows x 64 lanes
    int  soff[4];
    bool sval[4];   // wave-uniform (depends only on s>>6)
#pragma unroll
    for (int k = 0; k < 4; ++k) {
        int s     = k * 512 + tid;
        int c4    = s & 63;
        int row   = (s >> 6) & 7;
        int strip = s >> 9;
        int y     = strip * 64 + t0 - 2 + row;
        sval[k]   = (y >= 0) & (y < H);
        int yc    = min(max(y, 0), H - 1);
        soff[k]   = yc * W + c4 * 4;
    }

    unsigned outw[2][4];   // 2 px x 4 u32 (8 bf16 c2 values per px)
    const float4 z4 = make_float4(0.f, 0.f, 0.f, 0.f);

#pragma unroll
    for (int ci = 0; ci < 2; ++ci) {
        __syncthreads();   // protect xts reuse (and pad init on ci=0)
        const float* base = x + (size_t)(n * C + c0 + ci) * HWP;
#pragma unroll
        for (int k = 0; k < 4; ++k) {
            int s = k * 512 + tid;
            int rowflat = s >> 6;                       // wave-uniform
            if (sval[k]) {
                gload16(base + soff[k], &xts[rowflat * 272 + 4]);
            } else {
                *(float4*)&xts[rowflat * 272 + 4 + (s & 63) * 4] = z4;
            }
        }
        __syncthreads();   // drains vmcnt(0): DMA complete for all waves

        float sq[4][2];
#pragma unroll
        for (int q = 0; q < 4; ++q) {
            sq[q][0] = 0.f; sq[q][1] = 0.f;
        }

#pragma unroll 1
        for (int ph = 0; ph < 5; ++ph) {        // one kernel-row per phase
            float2 kwc[5];                      // 5 taps x 2 px = 10 VGPRs
#pragma unroll
            for (int j = 0; j < 5; ++j)
                kwc[j] = *(const float2*)(kb + (size_t)(ph * 5 + j) * HDWD);
#pragma unroll
            for (int q = 0; q < 4; ++q) {
                const float* rp = &xts[(q * 8 + rloc + ph) * 272 + wb + 2];
                float2 r0 = *(const float2*)(rp + 0);   // 8B-aligned b64
                float2 r1 = *(const float2*)(rp + 2);
                float2 r2 = *(const float2*)(rp + 4);
                float f[6] = {r0.x, r0.y, r1.x, r1.y, r2.x, r2.y};
#pragma unroll
                for (int j = 0; j < 5; ++j) {
                    const float2 kv = kwc[j];
                    sq[q][0] = fmaf(f[j + 0], kv.x, sq[q][0]);
                    sq[q][1] = fmaf(f[j + 1], kv.y, sq[q][1]);
                }
            }
        }
#pragma unroll
        for (int r = 0; r < 2; ++r) {
            outw[r][ci * 2 + 0] = pack2(sq[0][r], sq[1][r]);
            outw[r][ci * 2 + 1] = pack2(sq[2][r], sq[3][r]);
        }
    }

    // private slab: 2 px x 16B = 32B contiguous per thread
    u16* dst = out2p + ((size_t)(n * 32 + cc) * HDWD + hd * Wd + wd0) * 8;
    *(uint4*)(dst + 0) = make_uint4(outw[0][0], outw[0][1], outw[0][2], outw[0][3]);
    *(uint4*)(dst + 8) = make_uint4(outw[1][0], outw[1][1], outw[1][2], outw[1][3]);
}

// ---- Kernel D3: 1x1 out conv as MFMA GEMM (chunk-major A) ------------------
// A element (px, c2) lives at ((n*32 + (c2>>3))*HDWD + px)*8 + (c2&7); the
// bf16x8 fragment (c2 = s*32+q*8 .. +7) is exactly one 16B record chunk at
// plane 4s+q -> 256B-contiguous segments per 16-lane group.
__global__ __launch_bounds__(256) void kD3_out(const u16* __restrict__ out2p,
                                               const u16* __restrict__ bfr2,
                                               const float* __restrict__ ob,
                                               float* __restrict__ out) {
    const int tid = threadIdx.x;
    const int b   = blockIdx.x;
    const int px0g = b * 64;
    const int n    = px0g >> 14;
    const int px0  = px0g & (HDWD - 1);
    const int nt = tid >> 6;
    const int l  = tid & 63;
    const int c  = l & 15;
    const int q  = l >> 4;

    const u16* An = out2p + (size_t)n * 32 * HDWD * 8;

    f32x4 acc[4] = {{0.f,0.f,0.f,0.f},{0.f,0.f,0.f,0.f},
                    {0.f,0.f,0.f,0.f},{0.f,0.f,0.f,0.f}};
#pragma unroll
    for (int s = 0; s < 8; ++s) {
        bf16x8 bf = *(const bf16x8*)(bfr2 + ((size_t)(s * 4 + nt) * 64 + l) * 8);
#pragma unroll
        for (int mt = 0; mt < 4; ++mt) {
            const u16* ap = An + ((size_t)(4 * s + q) * HDWD + px0 + mt * 16 + c) * 8;
            bf16x8 a = *(const bf16x8*)ap;
            acc[mt] = __builtin_amdgcn_mfma_f32_16x16x32_bf16(a, bf, acc[mt], 0, 0, 0);
        }
    }
    const int co = nt * 16 + c;
    const float bias = ob[co];
    float* ob_ = out + (size_t)(n * OC + co) * HDWD + px0;
#pragma unroll
    for (int mt = 0; mt < 4; ++mt)
#pragma unroll
        for (int r = 0; r < 4; ++r)
            ob_[mt * 16 + q * 4 + r] = acc[mt][r] + bias;
}

extern "C" void kernel_launch(void* const* d_in, const int* in_sizes, int n_in,
                              void* d_out, int out_size, void* d_ws, size_t ws_size,
                              hipStream_t stream) {
    const float* x  = (const float*)d_in[0];
    const float* dw = (const float*)d_in[1];
    const float* db = (const float*)d_in[2];
    const float* ew = (const float*)d_in[3];
    const float* eb = (const float*)d_in[4];
    const float* ow = (const float*)d_in[5];
    const float* ob = (const float*)d_in[6];
    float* out = (float*)d_out;

    char* ws = (char*)d_ws;
    u16*   k1    = (u16*)ws;                              // [n][px][cm] 16.8 MB
    float* ksm   = (float*)(ws + 16777216);               // 3.3 MB
    u16*   out2p = (u16*)(ws + 16777216 + 3276800);       // [n][cc][px][8] 16.8 MB
    u16*   bfr   = out2p;          // 36 KB: kA-tail writes, kB2 reads, kC15 clobbers
    u16*   bfr2  = (u16*)(ws + 16777216 + 3276800 + 16777216); // 32 KB own slot

    kA_down <<<dim3(1024), dim3(256), 0, stream>>>(x, dw, db, k1, ew, ow, bfr, bfr2);
    kB2_enc <<<dim3(512),  dim3(256), 0, stream>>>(k1, bfr, eb, ksm);
    kC15_reassemble<<<dim3(1024), dim3(512), 0, stream>>>(x, ksm, out2p);
    kD3_out <<<dim3(512),  dim3(256), 0, stream>>>(out2p, bfr2, ob, out);
}